// Round 13
// baseline (340.929 us; speedup 1.0000x reference)
//
#include <hip/hip_runtime.h>
#include <hip/hip_bf16.h>

// Problem: B=4, S=4096, D=256 single-head causal attention, fp32 in/out.
// ALL tensors in MFMA-fragment order (fragment = contiguous 1KB, lane*16):
//  Qf @0:  strip s16=row>>4: 8KB; frag kk at (s16*8+kk)*1024.  Q is PRE-SCALED
//          by 1/16 (exact bf16 exponent shift) so attn skips the scale mul.
//  KV @8MB: per (batch, kv-tile t<64) 64KB: K frags [0..32K) (nf*8+kk)*1024;
//           V frags [32K..64K) (ks*16+n)*1024
//  O1/O2/O3 bf16 partials @24/32/40MB; ML fp32 [4][16384][2] @48MB.
// attn_fa2: 256 blocks x 512 thr (8 waves, 1 block/CU). 32 q-rows/wave (2
// strips sharing every K/V LDS read). Runs of 256 rows (u=0..15/batch,
// nt=4u+4); complement-paired tasks (u=p,cc)+(u=15-p,3-cc) -> 17 tiles/block.
// KV tile staged to LDS once (linear global_load_lds, dbuf, counted vmcnt).

#define SEQ 4096
#define DIM 256
#define NBATCH 4
#define KVBLK 64
#define KVT_BYTES 65536

#define QB_OFF   0
#define KV_OFF   (8u*1024*1024)
#define O1_OFF   (24u*1024*1024)
#define O2_OFF   (32u*1024*1024)
#define O3_OFF   (40u*1024*1024)
#define ML_OFF   (48u*1024*1024)

typedef __attribute__((ext_vector_type(8))) short bf16x8;
typedef __attribute__((ext_vector_type(4))) float f32x4;
typedef __attribute__((ext_vector_type(4))) unsigned short us4;

static __device__ inline unsigned short f2bf(float f) {
  unsigned int u = __float_as_uint(f);
  u += 0x7FFFu + ((u >> 16) & 1u);
  return (unsigned short)(u >> 16);
}
static __device__ inline float bf2f(unsigned short u) {
  return __uint_as_float(((unsigned int)u) << 16);
}

// ---------------- Kernel 1: QKV projection, fragment-order epilogues ----------------
__global__ __launch_bounds__(256) void qkv_gemm(
    const float* __restrict__ x, const float* __restrict__ Wq,
    const float* __restrict__ Wk, const float* __restrict__ Wv,
    char* __restrict__ qbf, char* __restrict__ kv)
{
  __shared__ unsigned short A_lds[128][40];
  __shared__ unsigned short B_lds[64][40];

  const int tid = threadIdx.x;
  const int lane = tid & 63;
  const int w = tid >> 6;
  const int lo = lane & 15, hi = lane >> 4;
  const int mb = blockIdx.x * 128;
  const int nb = blockIdx.y * 64;
  const int z = blockIdx.z;
  const float* Wm = (z == 0) ? Wq : (z == 1) ? Wk : Wv;

  f32x4 acc[2][4];
#pragma unroll
  for (int mi = 0; mi < 2; mi++)
#pragma unroll
    for (int ni = 0; ni < 4; ni++) acc[mi][ni] = (f32x4){0.f, 0.f, 0.f, 0.f};

  for (int ks = 0; ks < 8; ++ks) {
    const int k0 = ks * 32;
    __syncthreads();
#pragma unroll
    for (int i = 0; i < 4; ++i) {
      int f = tid + i * 256;
      int row = f >> 3, c4 = (f & 7) * 4;
      float4 v = *(const float4*)(x + (size_t)(mb + row) * DIM + k0 + c4);
      us4 bv = { f2bf(v.x), f2bf(v.y), f2bf(v.z), f2bf(v.w) };
      *(us4*)&A_lds[row][c4] = bv;
    }
#pragma unroll
    for (int i = 0; i < 2; ++i) {
      int f = tid + i * 256;
      int row = f >> 3, c4 = (f & 7) * 4;
      float4 v = *(const float4*)(Wm + (size_t)(nb + row) * DIM + k0 + c4);
      us4 bv = { f2bf(v.x), f2bf(v.y), f2bf(v.z), f2bf(v.w) };
      *(us4*)&B_lds[row][c4] = bv;
    }
    __syncthreads();
    bf16x8 a[2], bfr[4];
#pragma unroll
    for (int mi = 0; mi < 2; mi++) a[mi] = *(const bf16x8*)&A_lds[w * 32 + mi * 16 + lo][hi * 8];
#pragma unroll
    for (int ni = 0; ni < 4; ni++) bfr[ni] = *(const bf16x8*)&B_lds[ni * 16 + lo][hi * 8];
#pragma unroll
    for (int mi = 0; mi < 2; mi++)
#pragma unroll
      for (int ni = 0; ni < 4; ni++)
        acc[mi][ni] = __builtin_amdgcn_mfma_f32_16x16x32_bf16(a[mi], bfr[ni], acc[mi][ni], 0, 0, 0);
  }

  if (z == 0) {
    // Q fragment order, pre-scaled by 1/sqrt(D)=0.0625 (exact exponent shift)
#pragma unroll
    for (int mi = 0; mi < 2; mi++) {
      int r0 = mb + w * 32 + mi * 16 + hi * 4;
#pragma unroll
      for (int ni = 0; ni < 4; ni++) {
        int d = nb + ni * 16 + lo;
        int kkq = d >> 5, hiq = (d >> 3) & 3, eq = d & 7;
#pragma unroll
        for (int j = 0; j < 4; j++) {
          int srow = r0 + j;
          int s16 = srow >> 4, loq = srow & 15;
          size_t byte = ((size_t)(s16 * 8 + kkq) << 10) + ((hiq * 16 + loq) << 4) + eq * 2;
          *(unsigned short*)(qbf + byte) = f2bf(acc[mi][ni][j] * 0.0625f);
        }
      }
    }
  } else if (z == 1) {
    // K fragment order
#pragma unroll
    for (int mi = 0; mi < 2; mi++) {
      int r0 = mb + w * 32 + mi * 16 + hi * 4;
#pragma unroll
      for (int ni = 0; ni < 4; ni++) {
        int d = nb + ni * 16 + lo;
        int kkk = d >> 5, hik = (d >> 3) & 3, ek = d & 7;
#pragma unroll
        for (int j = 0; j < 4; j++) {
          int srow = r0 + j;
          int bb = srow >> 12, sl = srow & 4095;
          int t = sl >> 6, r = sl & 63;
          int nf = r >> 4, lok = r & 15;
          size_t byte = ((size_t)(bb * 64 + t)) * KVT_BYTES +
                        ((size_t)(nf * 8 + kkk) << 10) + ((hik * 16 + lok) << 4) + ek * 2;
          *(unsigned short*)(kv + byte) = f2bf(acc[mi][ni][j]);
        }
      }
    }
  } else {
    // V fragment order (8B stores)
#pragma unroll
    for (int mi = 0; mi < 2; mi++) {
      int s0 = mb + w * 32 + mi * 16 + hi * 4;
      int bb = s0 >> 12;
      int t = (s0 >> 6) & 63;
      int s_t = s0 & 63;
      int ksI = s_t >> 5;
      int hf = (s_t >> 3) & 3;
      int e0 = s_t & 7;
#pragma unroll
      for (int ni = 0; ni < 4; ni++) {
        int d = nb + ni * 16 + lo;
        int n = d >> 4;
        us4 pv = { f2bf(acc[mi][ni][0]), f2bf(acc[mi][ni][1]),
                   f2bf(acc[mi][ni][2]), f2bf(acc[mi][ni][3]) };
        size_t byte = ((size_t)(bb * 64 + t)) * KVT_BYTES + 32768 +
                      ((size_t)(ksI * 16 + n) << 10) + ((hf * 16 + lo) << 4) + e0 * 2;
        *(us4*)(kv + byte) = pv;
      }
    }
  }
}

// ---------------- Kernel 2a: attn_fa2 (8 waves x 32 rows, LDS-shared KV) ----------------
// 256 blocks x 512 thr. id&7=x: batch=x>>1, chunk-lsb=x&1. v=id>>3 (0..31):
// p=v&15, chunk-msb=v>>4. Tasks: (u=p, cc) then (u=15-p, 3-cc); nt=4u+4,
// chunk cc -> tiles [(u+1)cc, (u+1)(cc+1)). 17 tiles/block total.
__global__ __launch_bounds__(512, 2) void attn_fa2(
    const char* __restrict__ qbf, const char* __restrict__ kv,
    float* __restrict__ out, unsigned short* __restrict__ o1,
    unsigned short* __restrict__ o2, unsigned short* __restrict__ o3,
    float* __restrict__ ml)
{
  __shared__ char KV_lds[2][KVT_BYTES];        // 128KB double buffer (linear frags)
  __shared__ unsigned short P_lds[8][16][72];

  const int tid = threadIdx.x;
  const int lane = tid & 63;
  const int w = tid >> 6;
  const int lo = lane & 15, hi = lane >> 4;
  const int id = blockIdx.x;
  const int x = id & 7;
  const int b = x >> 1;
  const int v = id >> 3;
  const int p = v & 15;
  const int cbase = ((v >> 4) << 1) | (x & 1);   // 0..3

  const char* kv_base = kv + (size_t)b * 64 * KVT_BYTES;

  auto stageKV = [&](int t, int buf) {
    const char* src = kv_base + (size_t)t * KVT_BYTES + tid * 16;
    char* dst = &KV_lds[buf][0] + tid * 16;
#pragma unroll
    for (int i = 0; i < 8; ++i) {
      __builtin_amdgcn_global_load_lds(
          (const __attribute__((address_space(1))) void*)(src + i * 8192),
          (__attribute__((address_space(3))) void*)(dst + i * 8192),
          16, 0, 0);
    }
  };

  for (int task = 0; task < 2; ++task) {
    const int u = task ? (15 - p) : p;
    const int cc = task ? (3 - cbase) : cbase;
    const int nt = 4 * u + 4;
    const int t0 = (u + 1) * cc;
    const int t1 = (u + 1) * (cc + 1);
    const int qrow0 = u * 256 + w * 32;          // strip0 first row (in batch)
    const int rbase = b * SEQ + qrow0;
    float* mlc = ml + (size_t)cc * 16384 * 2;
    (void)nt;

    // Q fragments pinned: two strips (issued before stages; vmcnt-counted)
    bf16x8 qf0[8], qf1[8];
    {
      const char* qp0 = qbf + ((size_t)(b * 256 + u * 16 + w * 2) << 13) + lane * 16;
      const char* qp1 = qp0 + 8192;
#pragma unroll
      for (int kk = 0; kk < 8; kk++) {
        qf0[kk] = *(const bf16x8*)(qp0 + kk * 1024);
        qf1[kk] = *(const bf16x8*)(qp1 + kk * 1024);
      }
    }

    stageKV(t0, 0);
    if (t0 + 1 < t1) stageKV(t0 + 1, 1);

    float m0r[4], m1r[4], l0r[4], l1r[4];
#pragma unroll
    for (int j = 0; j < 4; j++) { m0r[j] = -3e38f; m1r[j] = -3e38f; l0r[j] = 0.f; l1r[j] = 0.f; }
    f32x4 oa0[16], oa1[16];
#pragma unroll
    for (int n = 0; n < 16; n++) { oa0[n] = (f32x4){0.f,0.f,0.f,0.f}; oa1[n] = (f32x4){0.f,0.f,0.f,0.f}; }

    for (int t = t0; t < t1; ++t) {
      const int cur = (t - t0) & 1;

      if (t + 1 < t1) {
        asm volatile("s_waitcnt vmcnt(8)" ::: "memory");
      } else {
        asm volatile("s_waitcnt vmcnt(0)" ::: "memory");
      }
      __builtin_amdgcn_sched_barrier(0);
      __builtin_amdgcn_s_barrier();   // buffer cur fully staged for all waves

      const char* kt = &KV_lds[cur][0] + lane * 16;

      // S = Q K^T: K frags from LDS in 4-reg halves, shared by both strips
      f32x4 sf0[4], sf1[4];
      __builtin_amdgcn_s_setprio(1);
#pragma unroll
      for (int nf = 0; nf < 4; nf++) {
        f32x4 a0 = (f32x4){0.f,0.f,0.f,0.f}, a1 = (f32x4){0.f,0.f,0.f,0.f};
#pragma unroll
        for (int h2 = 0; h2 < 2; h2++) {
          bf16x8 kfa[4];
#pragma unroll
          for (int k = 0; k < 4; k++)
            kfa[k] = *(const bf16x8*)(kt + ((nf * 8 + h2 * 4 + k) << 10));
#pragma unroll
          for (int k = 0; k < 4; k++) {
            a0 = __builtin_amdgcn_mfma_f32_16x16x32_bf16(qf0[h2 * 4 + k], kfa[k], a0, 0, 0, 0);
            a1 = __builtin_amdgcn_mfma_f32_16x16x32_bf16(qf1[h2 * 4 + k], kfa[k], a1, 0, 0, 0);
          }
        }
        sf0[nf] = a0; sf1[nf] = a1;
      }
      __builtin_amdgcn_s_setprio(0);

      // causal mask (Q pre-scaled; no scale mul needed)
      if ((t * KVBLK + KVBLK - 1) > qrow0) {
#pragma unroll
        for (int nf = 0; nf < 4; nf++) {
          int kg = t * KVBLK + nf * 16 + lo;
#pragma unroll
          for (int j = 0; j < 4; j++) {
            int qg = qrow0 + hi * 4 + j;
            if (kg > qg) sf0[nf][j] = -__builtin_inff();
            if (kg > qg + 16) sf1[nf][j] = -__builtin_inff();
          }
        }
      }

      // online softmax, defer-max, lazy l (per-lane partials, no in-loop reduce)
      float vn0[4], vn1[4];
#pragma unroll
      for (int j = 0; j < 4; j++) {
        float m = fmaxf(fmaxf(sf0[0][j], sf0[1][j]), fmaxf(sf0[2][j], sf0[3][j]));
        m = fmaxf(m, __shfl_xor(m, 1));
        m = fmaxf(m, __shfl_xor(m, 2));
        m = fmaxf(m, __shfl_xor(m, 4));
        m = fmaxf(m, __shfl_xor(m, 8));
        vn0[j] = m;
      }
#pragma unroll
      for (int j = 0; j < 4; j++) {
        float m = fmaxf(fmaxf(sf1[0][j], sf1[1][j]), fmaxf(sf1[2][j], sf1[3][j]));
        m = fmaxf(m, __shfl_xor(m, 1));
        m = fmaxf(m, __shfl_xor(m, 2));
        m = fmaxf(m, __shfl_xor(m, 4));
        m = fmaxf(m, __shfl_xor(m, 8));
        vn1[j] = m;
      }
      bool grow = false;
#pragma unroll
      for (int j = 0; j < 4; j++)
        grow = grow || (vn0[j] > m0r[j] + 8.f) || (vn1[j] > m1r[j] + 8.f);
      if (__any(grow)) {
#pragma unroll
        for (int j = 0; j < 4; j++) {
          float mn0 = fmaxf(m0r[j], vn0[j]);
          float mn1 = fmaxf(m1r[j], vn1[j]);
          float al0 = __expf(m0r[j] - mn0);
          float al1 = __expf(m1r[j] - mn1);
          m0r[j] = mn0; m1r[j] = mn1;
          l0r[j] *= al0; l1r[j] *= al1;
#pragma unroll
          for (int n = 0; n < 16; n++) { oa0[n][j] *= al0; oa1[n][j] *= al1; }
        }
      }
#pragma unroll
      for (int j = 0; j < 4; j++) {
        float s0 = 0.f, s1 = 0.f;
#pragma unroll
        for (int nf = 0; nf < 4; nf++) {
          sf0[nf][j] = __expf(sf0[nf][j] - m0r[j]); s0 += sf0[nf][j];
          sf1[nf][j] = __expf(sf1[nf][j] - m1r[j]); s1 += sf1[nf][j];
        }
        l0r[j] += s0; l1r[j] += s1;   // per-lane partials; reduced at epilogue
      }

      // P -> per-wave LDS roundtrip, strip-sequential
      bf16x8 pa00, pa01, pa10, pa11;
#pragma unroll
      for (int nf = 0; nf < 4; nf++)
#pragma unroll
        for (int j = 0; j < 4; j++)
          P_lds[w][hi * 4 + j][nf * 16 + lo] = f2bf(sf0[nf][j]);
      asm volatile("s_waitcnt lgkmcnt(0)" ::: "memory");
      __builtin_amdgcn_sched_barrier(0);
      pa00 = *(const bf16x8*)&P_lds[w][lo][hi * 8];
      pa01 = *(const bf16x8*)&P_lds[w][lo][32 + hi * 8];
      asm volatile("s_waitcnt lgkmcnt(0)" ::: "memory");
      __builtin_amdgcn_sched_barrier(0);
#pragma unroll
      for (int nf = 0; nf < 4; nf++)
#pragma unroll
        for (int j = 0; j < 4; j++)
          P_lds[w][hi * 4 + j][nf * 16 + lo] = f2bf(sf1[nf][j]);
      asm volatile("s_waitcnt lgkmcnt(0)" ::: "memory");
      __builtin_amdgcn_sched_barrier(0);
      pa10 = *(const bf16x8*)&P_lds[w][lo][hi * 8];
      pa11 = *(const bf16x8*)&P_lds[w][lo][32 + hi * 8];
      asm volatile("s_waitcnt lgkmcnt(0)" ::: "memory");
      __builtin_amdgcn_sched_barrier(0);

      // O += P V: V frags from LDS, shared by both strips
      const char* vt = &KV_lds[cur][32768] + lane * 16;
      __builtin_amdgcn_s_setprio(1);
#pragma unroll
      for (int g = 0; g < 4; g++) {
        bf16x8 va[4], vb[4];
#pragma unroll
        for (int k = 0; k < 4; k++) {
          int n = g * 4 + k;
          va[k] = *(const bf16x8*)(vt + (n << 10));
          vb[k] = *(const bf16x8*)(vt + ((16 + n) << 10));
        }
#pragma unroll
        for (int k = 0; k < 4; k++) {
          int n = g * 4 + k;
          oa0[n] = __builtin_amdgcn_mfma_f32_16x16x32_bf16(pa00, va[k], oa0[n], 0, 0, 0);
          oa0[n] = __builtin_amdgcn_mfma_f32_16x16x32_bf16(pa01, vb[k], oa0[n], 0, 0, 0);
          oa1[n] = __builtin_amdgcn_mfma_f32_16x16x32_bf16(pa10, va[k], oa1[n], 0, 0, 0);
          oa1[n] = __builtin_amdgcn_mfma_f32_16x16x32_bf16(pa11, vb[k], oa1[n], 0, 0, 0);
        }
      }
      __builtin_amdgcn_s_setprio(0);

      __builtin_amdgcn_sched_barrier(0);
      __builtin_amdgcn_s_barrier();   // all waves done reading buffer cur
      if (t + 2 < t1) stageKV(t + 2, cur);
    }

    // epilogue: reduce lazy-l across 16 lanes; cc==0 -> fp32 out else bf16 partial
    unsigned short* opc = (cc == 1) ? o1 : (cc == 2) ? o2 : o3;
#pragma unroll
    for (int sp = 0; sp < 2; sp++) {
#pragma unroll
      for (int j = 0; j < 4; j++) {
        float lsum = sp ? l1r[j] : l0r[j];
        lsum += __shfl_xor(lsum, 1);
        lsum += __shfl_xor(lsum, 2);
        lsum += __shfl_xor(lsum, 4);
        lsum += __shfl_xor(lsum, 8);
        float mrow = sp ? m1r[j] : m0r[j];
        int r = rbase + sp * 16 + hi * 4 + j;
        float inv = (lsum > 0.f) ? 1.f / lsum : 0.f;
        if (cc == 0) {
          float* orow = out + (size_t)r * DIM;
#pragma unroll
          for (int n = 0; n < 16; n++) {
            f32x4 o = sp ? oa1[n] : oa0[n];
            orow[n * 16 + lo] = o[j] * inv;
          }
        } else {
          unsigned short* orow = opc + (size_t)r * DIM;
#pragma unroll
          for (int n = 0; n < 16; n++) {
            f32x4 o = sp ? oa1[n] : oa0[n];
            orow[n * 16 + lo] = f2bf(o[j] * inv);
          }
        }
        if (lo == 0) {
          mlc[(size_t)r * 2 + 0] = mrow;
          mlc[(size_t)r * 2 + 1] = lsum;
        }
      }
    }
  }
}

// ---------------- Kernel 2b: 4-way merge ----------------
__global__ __launch_bounds__(256) void merge4(
    const float* __restrict__ ml,
    const unsigned short* __restrict__ o1, const unsigned short* __restrict__ o2,
    const unsigned short* __restrict__ o3, float* __restrict__ out)
{
  int r = blockIdx.x * 4 + (threadIdx.x >> 6);
  int c4 = (threadIdx.x & 63) * 4;
  float m0 = ml[(size_t)r*2],           l0 = ml[(size_t)r*2+1];
  float m1 = ml[(size_t)(16384+r)*2],   l1 = ml[(size_t)(16384+r)*2+1];
  float m2 = ml[(size_t)(32768+r)*2],   l2 = ml[(size_t)(32768+r)*2+1];
  float m3 = ml[(size_t)(49152+r)*2],   l3 = ml[(size_t)(49152+r)*2+1];
  float M = fmaxf(fmaxf(m0, m1), fmaxf(m2, m3));
  float w0 = l0 * __expf(m0 - M);
  float w1 = l1 * __expf(m1 - M);
  float w2 = l2 * __expf(m2 - M);
  float w3 = l3 * __expf(m3 - M);
  float inv = 1.f / (w0 + w1 + w2 + w3);
  float4 o0 = *(const float4*)(out + (size_t)r * DIM + c4);
  us4 a  = *(const us4*)(o1 + (size_t)r * DIM + c4);
  us4 bq = *(const us4*)(o2 + (size_t)r * DIM + c4);
  us4 cq = *(const us4*)(o3 + (size_t)r * DIM + c4);
  float4 res;
  res.x = (w0*o0.x + w1*bf2f(a.x) + w2*bf2f(bq.x) + w3*bf2f(cq.x)) * inv;
  res.y = (w0*o0.y + w1*bf2f(a.y) + w2*bf2f(bq.y) + w3*bf2f(cq.y)) * inv;
  res.z = (w0*o0.z + w1*bf2f(a.z) + w2*bf2f(bq.z) + w3*bf2f(cq.z)) * inv;
  res.w = (w0*o0.w + w1*bf2f(a.w) + w2*bf2f(bq.w) + w3*bf2f(cq.w)) * inv;
  *(float4*)(out + (size_t)r * DIM + c4) = res;
}

extern "C" void kernel_launch(void* const* d_in, const int* in_sizes, int n_in,
                              void* d_out, int out_size, void* d_ws, size_t ws_size,
                              hipStream_t stream) {
  const float* x  = (const float*)d_in[0];
  const float* Wq = (const float*)d_in[1];
  const float* Wk = (const float*)d_in[2];
  const float* Wv = (const float*)d_in[3];
  char* ws = (char*)d_ws;
  char* qbf = ws + QB_OFF;
  char* kv  = ws + KV_OFF;
  unsigned short* o1 = (unsigned short*)(ws + O1_OFF);
  unsigned short* o2 = (unsigned short*)(ws + O2_OFF);
  unsigned short* o3 = (unsigned short*)(ws + O3_OFF);
  float* ml = (float*)(ws + ML_OFF);
  float* out = (float*)d_out;

  qkv_gemm<<<dim3(128, 4, 3), 256, 0, stream>>>(x, Wq, Wk, Wv, qbf, kv);
  attn_fa2<<<dim3(256), 512, 0, stream>>>(qbf, kv, out, o1, o2, o3, ml);
  merge4<<<dim3(4096), 256, 0, stream>>>(ml, o1, o2, o3, out);
}

// Round 14
// 340.736 us; speedup vs baseline: 1.0006x; 1.0006x over previous
//
#include <hip/hip_runtime.h>
#include <hip/hip_bf16.h>

// Problem: B=4, S=4096, D=256 single-head causal attention, fp32 in/out.
// ALL tensors in MFMA-fragment order (fragment = contiguous 1KB, lane*16):
//  Qf @0:  strip s16=row>>4: 8KB; frag kk at (s16*8+kk)*1024.  Q is PRE-SCALED
//          by 1/16 (exact bf16 exponent shift) so attn skips the scale mul.
//  KV @8MB: per (batch, kv-tile t<64) 64KB: K frags [0..32K) (nf*8+kk)*1024;
//           V frags [32K..64K) (ks*16+n)*1024
//  O1/O2/O3 bf16 partials @24/32/40MB; ML fp32 [4][16384][2] @48MB.
// attn_fa2: 256 blocks x 512 thr (8 waves, 1 block/CU — LDS 146KB forces it).
// 32 q-rows/wave (2 strips sharing every K/V LDS read). Runs of 256 rows
// (u=0..15/batch, nt=4u+4); complement-paired tasks (u=p,cc)+(u=15-p,3-cc)
// -> 17 tiles/block. KV tile staged once (linear global_load_lds, dbuf,
// counted vmcnt). R13 LESSON: launch_bounds 2nd arg is waves/EU — asking 2
// capped VGPR at 128 and spilled 1.3GB to scratch. (512,1) = 256 VGPR cap.

#define SEQ 4096
#define DIM 256
#define NBATCH 4
#define KVBLK 64
#define KVT_BYTES 65536

#define QB_OFF   0
#define KV_OFF   (8u*1024*1024)
#define O1_OFF   (24u*1024*1024)
#define O2_OFF   (32u*1024*1024)
#define O3_OFF   (40u*1024*1024)
#define ML_OFF   (48u*1024*1024)

typedef __attribute__((ext_vector_type(8))) short bf16x8;
typedef __attribute__((ext_vector_type(4))) float f32x4;
typedef __attribute__((ext_vector_type(4))) unsigned short us4;

static __device__ inline unsigned short f2bf(float f) {
  unsigned int u = __float_as_uint(f);
  u += 0x7FFFu + ((u >> 16) & 1u);
  return (unsigned short)(u >> 16);
}
static __device__ inline float bf2f(unsigned short u) {
  return __uint_as_float(((unsigned int)u) << 16);
}

// ---------------- Kernel 1: QKV projection, fragment-order epilogues ----------------
__global__ __launch_bounds__(256) void qkv_gemm(
    const float* __restrict__ x, const float* __restrict__ Wq,
    const float* __restrict__ Wk, const float* __restrict__ Wv,
    char* __restrict__ qbf, char* __restrict__ kv)
{
  __shared__ unsigned short A_lds[128][40];
  __shared__ unsigned short B_lds[64][40];

  const int tid = threadIdx.x;
  const int lane = tid & 63;
  const int w = tid >> 6;
  const int lo = lane & 15, hi = lane >> 4;
  const int mb = blockIdx.x * 128;
  const int nb = blockIdx.y * 64;
  const int z = blockIdx.z;
  const float* Wm = (z == 0) ? Wq : (z == 1) ? Wk : Wv;

  f32x4 acc[2][4];
#pragma unroll
  for (int mi = 0; mi < 2; mi++)
#pragma unroll
    for (int ni = 0; ni < 4; ni++) acc[mi][ni] = (f32x4){0.f, 0.f, 0.f, 0.f};

  for (int ks = 0; ks < 8; ++ks) {
    const int k0 = ks * 32;
    __syncthreads();
#pragma unroll
    for (int i = 0; i < 4; ++i) {
      int f = tid + i * 256;
      int row = f >> 3, c4 = (f & 7) * 4;
      float4 v = *(const float4*)(x + (size_t)(mb + row) * DIM + k0 + c4);
      us4 bv = { f2bf(v.x), f2bf(v.y), f2bf(v.z), f2bf(v.w) };
      *(us4*)&A_lds[row][c4] = bv;
    }
#pragma unroll
    for (int i = 0; i < 2; ++i) {
      int f = tid + i * 256;
      int row = f >> 3, c4 = (f & 7) * 4;
      float4 v = *(const float4*)(Wm + (size_t)(nb + row) * DIM + k0 + c4);
      us4 bv = { f2bf(v.x), f2bf(v.y), f2bf(v.z), f2bf(v.w) };
      *(us4*)&B_lds[row][c4] = bv;
    }
    __syncthreads();
    bf16x8 a[2], bfr[4];
#pragma unroll
    for (int mi = 0; mi < 2; mi++) a[mi] = *(const bf16x8*)&A_lds[w * 32 + mi * 16 + lo][hi * 8];
#pragma unroll
    for (int ni = 0; ni < 4; ni++) bfr[ni] = *(const bf16x8*)&B_lds[ni * 16 + lo][hi * 8];
#pragma unroll
    for (int mi = 0; mi < 2; mi++)
#pragma unroll
      for (int ni = 0; ni < 4; ni++)
        acc[mi][ni] = __builtin_amdgcn_mfma_f32_16x16x32_bf16(a[mi], bfr[ni], acc[mi][ni], 0, 0, 0);
  }

  if (z == 0) {
    // Q fragment order, pre-scaled by 1/sqrt(D)=0.0625 (exact exponent shift)
#pragma unroll
    for (int mi = 0; mi < 2; mi++) {
      int r0 = mb + w * 32 + mi * 16 + hi * 4;
#pragma unroll
      for (int ni = 0; ni < 4; ni++) {
        int d = nb + ni * 16 + lo;
        int kkq = d >> 5, hiq = (d >> 3) & 3, eq = d & 7;
#pragma unroll
        for (int j = 0; j < 4; j++) {
          int srow = r0 + j;
          int s16 = srow >> 4, loq = srow & 15;
          size_t byte = ((size_t)(s16 * 8 + kkq) << 10) + ((hiq * 16 + loq) << 4) + eq * 2;
          *(unsigned short*)(qbf + byte) = f2bf(acc[mi][ni][j] * 0.0625f);
        }
      }
    }
  } else if (z == 1) {
    // K fragment order
#pragma unroll
    for (int mi = 0; mi < 2; mi++) {
      int r0 = mb + w * 32 + mi * 16 + hi * 4;
#pragma unroll
      for (int ni = 0; ni < 4; ni++) {
        int d = nb + ni * 16 + lo;
        int kkk = d >> 5, hik = (d >> 3) & 3, ek = d & 7;
#pragma unroll
        for (int j = 0; j < 4; j++) {
          int srow = r0 + j;
          int bb = srow >> 12, sl = srow & 4095;
          int t = sl >> 6, r = sl & 63;
          int nf = r >> 4, lok = r & 15;
          size_t byte = ((size_t)(bb * 64 + t)) * KVT_BYTES +
                        ((size_t)(nf * 8 + kkk) << 10) + ((hik * 16 + lok) << 4) + ek * 2;
          *(unsigned short*)(kv + byte) = f2bf(acc[mi][ni][j]);
        }
      }
    }
  } else {
    // V fragment order (8B stores)
#pragma unroll
    for (int mi = 0; mi < 2; mi++) {
      int s0 = mb + w * 32 + mi * 16 + hi * 4;
      int bb = s0 >> 12;
      int t = (s0 >> 6) & 63;
      int s_t = s0 & 63;
      int ksI = s_t >> 5;
      int hf = (s_t >> 3) & 3;
      int e0 = s_t & 7;
#pragma unroll
      for (int ni = 0; ni < 4; ni++) {
        int d = nb + ni * 16 + lo;
        int n = d >> 4;
        us4 pv = { f2bf(acc[mi][ni][0]), f2bf(acc[mi][ni][1]),
                   f2bf(acc[mi][ni][2]), f2bf(acc[mi][ni][3]) };
        size_t byte = ((size_t)(bb * 64 + t)) * KVT_BYTES + 32768 +
                      ((size_t)(ksI * 16 + n) << 10) + ((hf * 16 + lo) << 4) + e0 * 2;
        *(us4*)(kv + byte) = pv;
      }
    }
  }
}

// ---------------- Kernel 2a: attn_fa2 (8 waves x 32 rows, LDS-shared KV) ----------------
// 256 blocks x 512 thr. id&7=x: batch=x>>1, chunk-lsb=x&1. v=id>>3 (0..31):
// p=v&15, chunk-msb=v>>4. Tasks: (u=p, cc) then (u=15-p, 3-cc); nt=4u+4,
// chunk cc -> tiles [(u+1)cc, (u+1)(cc+1)). 17 tiles/block total.
__global__ __launch_bounds__(512, 1) void attn_fa2(
    const char* __restrict__ qbf, const char* __restrict__ kv,
    float* __restrict__ out, unsigned short* __restrict__ o1,
    unsigned short* __restrict__ o2, unsigned short* __restrict__ o3,
    float* __restrict__ ml)
{
  __shared__ char KV_lds[2][KVT_BYTES];        // 128KB double buffer (linear frags)
  __shared__ unsigned short P_lds[8][16][72];

  const int tid = threadIdx.x;
  const int lane = tid & 63;
  const int w = tid >> 6;
  const int lo = lane & 15, hi = lane >> 4;
  const int id = blockIdx.x;
  const int x = id & 7;
  const int b = x >> 1;
  const int v = id >> 3;
  const int p = v & 15;
  const int cbase = ((v >> 4) << 1) | (x & 1);   // 0..3

  const char* kv_base = kv + (size_t)b * 64 * KVT_BYTES;

  auto stageKV = [&](int t, int buf) {
    const char* src = kv_base + (size_t)t * KVT_BYTES + tid * 16;
    char* dst = &KV_lds[buf][0] + tid * 16;
#pragma unroll
    for (int i = 0; i < 8; ++i) {
      __builtin_amdgcn_global_load_lds(
          (const __attribute__((address_space(1))) void*)(src + i * 8192),
          (__attribute__((address_space(3))) void*)(dst + i * 8192),
          16, 0, 0);
    }
  };

  for (int task = 0; task < 2; ++task) {
    const int u = task ? (15 - p) : p;
    const int cc = task ? (3 - cbase) : cbase;
    const int t0 = (u + 1) * cc;
    const int t1 = (u + 1) * (cc + 1);
    const int qrow0 = u * 256 + w * 32;          // strip0 first row (in batch)
    const int rbase = b * SEQ + qrow0;
    float* mlc = ml + (size_t)cc * 16384 * 2;

    // Q fragments pinned: two strips (issued before stages; vmcnt-counted)
    bf16x8 qf0[8], qf1[8];
    {
      const char* qp0 = qbf + ((size_t)(b * 256 + u * 16 + w * 2) << 13) + lane * 16;
      const char* qp1 = qp0 + 8192;
#pragma unroll
      for (int kk = 0; kk < 8; kk++) {
        qf0[kk] = *(const bf16x8*)(qp0 + kk * 1024);
        qf1[kk] = *(const bf16x8*)(qp1 + kk * 1024);
      }
    }

    stageKV(t0, 0);
    if (t0 + 1 < t1) stageKV(t0 + 1, 1);

    float m0r[4], m1r[4], l0r[4], l1r[4];
#pragma unroll
    for (int j = 0; j < 4; j++) { m0r[j] = -3e38f; m1r[j] = -3e38f; l0r[j] = 0.f; l1r[j] = 0.f; }
    f32x4 oa0[16], oa1[16];
#pragma unroll
    for (int n = 0; n < 16; n++) { oa0[n] = (f32x4){0.f,0.f,0.f,0.f}; oa1[n] = (f32x4){0.f,0.f,0.f,0.f}; }

    for (int t = t0; t < t1; ++t) {
      const int cur = (t - t0) & 1;

      if (t + 1 < t1) {
        asm volatile("s_waitcnt vmcnt(8)" ::: "memory");
      } else {
        asm volatile("s_waitcnt vmcnt(0)" ::: "memory");
      }
      __builtin_amdgcn_sched_barrier(0);
      __builtin_amdgcn_s_barrier();   // buffer cur fully staged for all waves

      const char* kt = &KV_lds[cur][0] + lane * 16;

      // S = Q K^T: K frags from LDS in 4-reg halves, shared by both strips
      f32x4 sf0[4], sf1[4];
      __builtin_amdgcn_s_setprio(1);
#pragma unroll
      for (int nf = 0; nf < 4; nf++) {
        f32x4 a0 = (f32x4){0.f,0.f,0.f,0.f}, a1 = (f32x4){0.f,0.f,0.f,0.f};
#pragma unroll
        for (int h2 = 0; h2 < 2; h2++) {
          bf16x8 kfa[4];
#pragma unroll
          for (int k = 0; k < 4; k++)
            kfa[k] = *(const bf16x8*)(kt + ((nf * 8 + h2 * 4 + k) << 10));
#pragma unroll
          for (int k = 0; k < 4; k++) {
            a0 = __builtin_amdgcn_mfma_f32_16x16x32_bf16(qf0[h2 * 4 + k], kfa[k], a0, 0, 0, 0);
            a1 = __builtin_amdgcn_mfma_f32_16x16x32_bf16(qf1[h2 * 4 + k], kfa[k], a1, 0, 0, 0);
          }
        }
        sf0[nf] = a0; sf1[nf] = a1;
      }
      __builtin_amdgcn_s_setprio(0);

      // causal mask (Q pre-scaled; no scale mul needed)
      if ((t * KVBLK + KVBLK - 1) > qrow0) {
#pragma unroll
        for (int nf = 0; nf < 4; nf++) {
          int kg = t * KVBLK + nf * 16 + lo;
#pragma unroll
          for (int j = 0; j < 4; j++) {
            int qg = qrow0 + hi * 4 + j;
            if (kg > qg) sf0[nf][j] = -__builtin_inff();
            if (kg > qg + 16) sf1[nf][j] = -__builtin_inff();
          }
        }
      }

      // online softmax, defer-max, lazy l (per-lane partials, no in-loop reduce)
      float vn0[4], vn1[4];
#pragma unroll
      for (int j = 0; j < 4; j++) {
        float m = fmaxf(fmaxf(sf0[0][j], sf0[1][j]), fmaxf(sf0[2][j], sf0[3][j]));
        m = fmaxf(m, __shfl_xor(m, 1));
        m = fmaxf(m, __shfl_xor(m, 2));
        m = fmaxf(m, __shfl_xor(m, 4));
        m = fmaxf(m, __shfl_xor(m, 8));
        vn0[j] = m;
      }
#pragma unroll
      for (int j = 0; j < 4; j++) {
        float m = fmaxf(fmaxf(sf1[0][j], sf1[1][j]), fmaxf(sf1[2][j], sf1[3][j]));
        m = fmaxf(m, __shfl_xor(m, 1));
        m = fmaxf(m, __shfl_xor(m, 2));
        m = fmaxf(m, __shfl_xor(m, 4));
        m = fmaxf(m, __shfl_xor(m, 8));
        vn1[j] = m;
      }
      bool grow = false;
#pragma unroll
      for (int j = 0; j < 4; j++)
        grow = grow || (vn0[j] > m0r[j] + 8.f) || (vn1[j] > m1r[j] + 8.f);
      if (__any(grow)) {
#pragma unroll
        for (int j = 0; j < 4; j++) {
          float mn0 = fmaxf(m0r[j], vn0[j]);
          float mn1 = fmaxf(m1r[j], vn1[j]);
          float al0 = __expf(m0r[j] - mn0);
          float al1 = __expf(m1r[j] - mn1);
          m0r[j] = mn0; m1r[j] = mn1;
          l0r[j] *= al0; l1r[j] *= al1;
#pragma unroll
          for (int n = 0; n < 16; n++) { oa0[n][j] *= al0; oa1[n][j] *= al1; }
        }
      }
#pragma unroll
      for (int j = 0; j < 4; j++) {
        float s0 = 0.f, s1 = 0.f;
#pragma unroll
        for (int nf = 0; nf < 4; nf++) {
          sf0[nf][j] = __expf(sf0[nf][j] - m0r[j]); s0 += sf0[nf][j];
          sf1[nf][j] = __expf(sf1[nf][j] - m1r[j]); s1 += sf1[nf][j];
        }
        l0r[j] += s0; l1r[j] += s1;   // per-lane partials; reduced at epilogue
      }

      // P -> per-wave LDS roundtrip, strip-sequential
      bf16x8 pa00, pa01, pa10, pa11;
#pragma unroll
      for (int nf = 0; nf < 4; nf++)
#pragma unroll
        for (int j = 0; j < 4; j++)
          P_lds[w][hi * 4 + j][nf * 16 + lo] = f2bf(sf0[nf][j]);
      asm volatile("s_waitcnt lgkmcnt(0)" ::: "memory");
      __builtin_amdgcn_sched_barrier(0);
      pa00 = *(const bf16x8*)&P_lds[w][lo][hi * 8];
      pa01 = *(const bf16x8*)&P_lds[w][lo][32 + hi * 8];
      asm volatile("s_waitcnt lgkmcnt(0)" ::: "memory");
      __builtin_amdgcn_sched_barrier(0);
#pragma unroll
      for (int nf = 0; nf < 4; nf++)
#pragma unroll
        for (int j = 0; j < 4; j++)
          P_lds[w][hi * 4 + j][nf * 16 + lo] = f2bf(sf1[nf][j]);
      asm volatile("s_waitcnt lgkmcnt(0)" ::: "memory");
      __builtin_amdgcn_sched_barrier(0);
      pa10 = *(const bf16x8*)&P_lds[w][lo][hi * 8];
      pa11 = *(const bf16x8*)&P_lds[w][lo][32 + hi * 8];
      asm volatile("s_waitcnt lgkmcnt(0)" ::: "memory");
      __builtin_amdgcn_sched_barrier(0);

      // O += P V: V frags from LDS, shared by both strips
      const char* vt = &KV_lds[cur][32768] + lane * 16;
      __builtin_amdgcn_s_setprio(1);
#pragma unroll
      for (int g = 0; g < 4; g++) {
        bf16x8 va[4], vb[4];
#pragma unroll
        for (int k = 0; k < 4; k++) {
          int n = g * 4 + k;
          va[k] = *(const bf16x8*)(vt + (n << 10));
          vb[k] = *(const bf16x8*)(vt + ((16 + n) << 10));
        }
#pragma unroll
        for (int k = 0; k < 4; k++) {
          int n = g * 4 + k;
          oa0[n] = __builtin_amdgcn_mfma_f32_16x16x32_bf16(pa00, va[k], oa0[n], 0, 0, 0);
          oa0[n] = __builtin_amdgcn_mfma_f32_16x16x32_bf16(pa01, vb[k], oa0[n], 0, 0, 0);
          oa1[n] = __builtin_amdgcn_mfma_f32_16x16x32_bf16(pa10, va[k], oa1[n], 0, 0, 0);
          oa1[n] = __builtin_amdgcn_mfma_f32_16x16x32_bf16(pa11, vb[k], oa1[n], 0, 0, 0);
        }
      }
      __builtin_amdgcn_s_setprio(0);

      __builtin_amdgcn_sched_barrier(0);
      __builtin_amdgcn_s_barrier();   // all waves done reading buffer cur
      if (t + 2 < t1) stageKV(t + 2, cur);
    }

    // epilogue: reduce lazy-l across 16 lanes; cc==0 -> fp32 out else bf16 partial
    unsigned short* opc = (cc == 1) ? o1 : (cc == 2) ? o2 : o3;
#pragma unroll
    for (int sp = 0; sp < 2; sp++) {
#pragma unroll
      for (int j = 0; j < 4; j++) {
        float lsum = sp ? l1r[j] : l0r[j];
        lsum += __shfl_xor(lsum, 1);
        lsum += __shfl_xor(lsum, 2);
        lsum += __shfl_xor(lsum, 4);
        lsum += __shfl_xor(lsum, 8);
        float mrow = sp ? m1r[j] : m0r[j];
        int r = rbase + sp * 16 + hi * 4 + j;
        float inv = (lsum > 0.f) ? 1.f / lsum : 0.f;
        if (cc == 0) {
          float* orow = out + (size_t)r * DIM;
#pragma unroll
          for (int n = 0; n < 16; n++) {
            f32x4 o = sp ? oa1[n] : oa0[n];
            orow[n * 16 + lo] = o[j] * inv;
          }
        } else {
          unsigned short* orow = opc + (size_t)r * DIM;
#pragma unroll
          for (int n = 0; n < 16; n++) {
            f32x4 o = sp ? oa1[n] : oa0[n];
            orow[n * 16 + lo] = f2bf(o[j] * inv);
          }
        }
        if (lo == 0) {
          mlc[(size_t)r * 2 + 0] = mrow;
          mlc[(size_t)r * 2 + 1] = lsum;
        }
      }
    }
  }
}

// ---------------- Kernel 2b: 4-way merge ----------------
__global__ __launch_bounds__(256) void merge4(
    const float* __restrict__ ml,
    const unsigned short* __restrict__ o1, const unsigned short* __restrict__ o2,
    const unsigned short* __restrict__ o3, float* __restrict__ out)
{
  int r = blockIdx.x * 4 + (threadIdx.x >> 6);
  int c4 = (threadIdx.x & 63) * 4;
  float m0 = ml[(size_t)r*2],           l0 = ml[(size_t)r*2+1];
  float m1 = ml[(size_t)(16384+r)*2],   l1 = ml[(size_t)(16384+r)*2+1];
  float m2 = ml[(size_t)(32768+r)*2],   l2 = ml[(size_t)(32768+r)*2+1];
  float m3 = ml[(size_t)(49152+r)*2],   l3 = ml[(size_t)(49152+r)*2+1];
  float M = fmaxf(fmaxf(m0, m1), fmaxf(m2, m3));
  float w0 = l0 * __expf(m0 - M);
  float w1 = l1 * __expf(m1 - M);
  float w2 = l2 * __expf(m2 - M);
  float w3 = l3 * __expf(m3 - M);
  float inv = 1.f / (w0 + w1 + w2 + w3);
  float4 o0 = *(const float4*)(out + (size_t)r * DIM + c4);
  us4 a  = *(const us4*)(o1 + (size_t)r * DIM + c4);
  us4 bq = *(const us4*)(o2 + (size_t)r * DIM + c4);
  us4 cq = *(const us4*)(o3 + (size_t)r * DIM + c4);
  float4 res;
  res.x = (w0*o0.x + w1*bf2f(a.x) + w2*bf2f(bq.x) + w3*bf2f(cq.x)) * inv;
  res.y = (w0*o0.y + w1*bf2f(a.y) + w2*bf2f(bq.y) + w3*bf2f(cq.y)) * inv;
  res.z = (w0*o0.z + w1*bf2f(a.z) + w2*bf2f(bq.z) + w3*bf2f(cq.z)) * inv;
  res.w = (w0*o0.w + w1*bf2f(a.w) + w2*bf2f(bq.w) + w3*bf2f(cq.w)) * inv;
  *(float4*)(out + (size_t)r * DIM + c4) = res;
}

extern "C" void kernel_launch(void* const* d_in, const int* in_sizes, int n_in,
                              void* d_out, int out_size, void* d_ws, size_t ws_size,
                              hipStream_t stream) {
  const float* x  = (const float*)d_in[0];
  const float* Wq = (const float*)d_in[1];
  const float* Wk = (const float*)d_in[2];
  const float* Wv = (const float*)d_in[3];
  char* ws = (char*)d_ws;
  char* qbf = ws + QB_OFF;
  char* kv  = ws + KV_OFF;
  unsigned short* o1 = (unsigned short*)(ws + O1_OFF);
  unsigned short* o2 = (unsigned short*)(ws + O2_OFF);
  unsigned short* o3 = (unsigned short*)(ws + O3_OFF);
  float* ml = (float*)(ws + ML_OFF);
  float* out = (float*)d_out;

  qkv_gemm<<<dim3(128, 4, 3), 256, 0, stream>>>(x, Wq, Wk, Wv, qbf, kv);
  attn_fa2<<<dim3(256), 512, 0, stream>>>(qbf, kv, out, o1, o2, o3, ml);
  merge4<<<dim3(4096), 256, 0, stream>>>(ml, o1, o2, o3, out);
}

// Round 15
// 146.288 us; speedup vs baseline: 2.3305x; 2.3292x over previous
//
#include <hip/hip_runtime.h>
#include <hip/hip_bf16.h>

// Problem: B=4, S=4096, D=256 single-head causal attention, fp32 in/out.
// ALL tensors in MFMA-fragment order (fragment = contiguous 1KB, lane*16):
//  Qf @0:  strip s16=row>>4: 8KB; frag kk at (s16*8+kk)*1024.  Q PRE-SCALED by 1/16.
//  KV @8MB: per (batch, kv-tile t<64) 64KB: K frags [0..32K) (nf*8+kk)*1024;
//           V frags [32K..64K) (ks*16+n)*1024
//  O1/O2/O3 bf16 partials @24/32/40MB; ML fp32 [4][16384][2] @48MB.
// attn_fa3: 256 blocks x 256 thr (4 waves, 1 block/CU, 1 wave/SIMD).
// R13/R14 LESSON: an 8-wave block forces 2 waves/SIMD -> 256-reg cap -> the
// 2-strip kernel (~300 live regs) spills 1.3GB. A 4-wave block allows the
// full 512-reg file per wave: 2 strips (32 q-rows/wave) fit spill-free.
// Same tile-visits as R12 (4224) but HALF the LDS reads per visit.
// Runs of 128 rows (u=0..31, nt=2u+2); pairs (u=p,cc)+(u=31-p,3-cc).

#define SEQ 4096
#define DIM 256
#define NBATCH 4
#define KVBLK 64
#define KVT_BYTES 65536

#define QB_OFF   0
#define KV_OFF   (8u*1024*1024)
#define O1_OFF   (24u*1024*1024)
#define O2_OFF   (32u*1024*1024)
#define O3_OFF   (40u*1024*1024)
#define ML_OFF   (48u*1024*1024)

typedef __attribute__((ext_vector_type(8))) short bf16x8;
typedef __attribute__((ext_vector_type(4))) float f32x4;
typedef __attribute__((ext_vector_type(4))) unsigned short us4;

static __device__ inline unsigned short f2bf(float f) {
  unsigned int u = __float_as_uint(f);
  u += 0x7FFFu + ((u >> 16) & 1u);
  return (unsigned short)(u >> 16);
}
static __device__ inline float bf2f(unsigned short u) {
  return __uint_as_float(((unsigned int)u) << 16);
}

// ---------------- Kernel 1: QKV projection, fragment-order epilogues ----------------
__global__ __launch_bounds__(256) void qkv_gemm(
    const float* __restrict__ x, const float* __restrict__ Wq,
    const float* __restrict__ Wk, const float* __restrict__ Wv,
    char* __restrict__ qbf, char* __restrict__ kv)
{
  __shared__ unsigned short A_lds[128][40];
  __shared__ unsigned short B_lds[64][40];

  const int tid = threadIdx.x;
  const int lane = tid & 63;
  const int w = tid >> 6;
  const int lo = lane & 15, hi = lane >> 4;
  const int mb = blockIdx.x * 128;
  const int nb = blockIdx.y * 64;
  const int z = blockIdx.z;
  const float* Wm = (z == 0) ? Wq : (z == 1) ? Wk : Wv;

  f32x4 acc[2][4];
#pragma unroll
  for (int mi = 0; mi < 2; mi++)
#pragma unroll
    for (int ni = 0; ni < 4; ni++) acc[mi][ni] = (f32x4){0.f, 0.f, 0.f, 0.f};

  for (int ks = 0; ks < 8; ++ks) {
    const int k0 = ks * 32;
    __syncthreads();
#pragma unroll
    for (int i = 0; i < 4; ++i) {
      int f = tid + i * 256;
      int row = f >> 3, c4 = (f & 7) * 4;
      float4 v = *(const float4*)(x + (size_t)(mb + row) * DIM + k0 + c4);
      us4 bv = { f2bf(v.x), f2bf(v.y), f2bf(v.z), f2bf(v.w) };
      *(us4*)&A_lds[row][c4] = bv;
    }
#pragma unroll
    for (int i = 0; i < 2; ++i) {
      int f = tid + i * 256;
      int row = f >> 3, c4 = (f & 7) * 4;
      float4 v = *(const float4*)(Wm + (size_t)(nb + row) * DIM + k0 + c4);
      us4 bv = { f2bf(v.x), f2bf(v.y), f2bf(v.z), f2bf(v.w) };
      *(us4*)&B_lds[row][c4] = bv;
    }
    __syncthreads();
    bf16x8 a[2], bfr[4];
#pragma unroll
    for (int mi = 0; mi < 2; mi++) a[mi] = *(const bf16x8*)&A_lds[w * 32 + mi * 16 + lo][hi * 8];
#pragma unroll
    for (int ni = 0; ni < 4; ni++) bfr[ni] = *(const bf16x8*)&B_lds[ni * 16 + lo][hi * 8];
#pragma unroll
    for (int mi = 0; mi < 2; mi++)
#pragma unroll
      for (int ni = 0; ni < 4; ni++)
        acc[mi][ni] = __builtin_amdgcn_mfma_f32_16x16x32_bf16(a[mi], bfr[ni], acc[mi][ni], 0, 0, 0);
  }

  if (z == 0) {
    // Q fragment order, pre-scaled by 1/sqrt(D)=0.0625 (exact exponent shift)
#pragma unroll
    for (int mi = 0; mi < 2; mi++) {
      int r0 = mb + w * 32 + mi * 16 + hi * 4;
#pragma unroll
      for (int ni = 0; ni < 4; ni++) {
        int d = nb + ni * 16 + lo;
        int kkq = d >> 5, hiq = (d >> 3) & 3, eq = d & 7;
#pragma unroll
        for (int j = 0; j < 4; j++) {
          int srow = r0 + j;
          int s16 = srow >> 4, loq = srow & 15;
          size_t byte = ((size_t)(s16 * 8 + kkq) << 10) + ((hiq * 16 + loq) << 4) + eq * 2;
          *(unsigned short*)(qbf + byte) = f2bf(acc[mi][ni][j] * 0.0625f);
        }
      }
    }
  } else if (z == 1) {
    // K fragment order
#pragma unroll
    for (int mi = 0; mi < 2; mi++) {
      int r0 = mb + w * 32 + mi * 16 + hi * 4;
#pragma unroll
      for (int ni = 0; ni < 4; ni++) {
        int d = nb + ni * 16 + lo;
        int kkk = d >> 5, hik = (d >> 3) & 3, ek = d & 7;
#pragma unroll
        for (int j = 0; j < 4; j++) {
          int srow = r0 + j;
          int bb = srow >> 12, sl = srow & 4095;
          int t = sl >> 6, r = sl & 63;
          int nf = r >> 4, lok = r & 15;
          size_t byte = ((size_t)(bb * 64 + t)) * KVT_BYTES +
                        ((size_t)(nf * 8 + kkk) << 10) + ((hik * 16 + lok) << 4) + ek * 2;
          *(unsigned short*)(kv + byte) = f2bf(acc[mi][ni][j]);
        }
      }
    }
  } else {
    // V fragment order (8B stores)
#pragma unroll
    for (int mi = 0; mi < 2; mi++) {
      int s0 = mb + w * 32 + mi * 16 + hi * 4;
      int bb = s0 >> 12;
      int t = (s0 >> 6) & 63;
      int s_t = s0 & 63;
      int ksI = s_t >> 5;
      int hf = (s_t >> 3) & 3;
      int e0 = s_t & 7;
#pragma unroll
      for (int ni = 0; ni < 4; ni++) {
        int d = nb + ni * 16 + lo;
        int n = d >> 4;
        us4 pv = { f2bf(acc[mi][ni][0]), f2bf(acc[mi][ni][1]),
                   f2bf(acc[mi][ni][2]), f2bf(acc[mi][ni][3]) };
        size_t byte = ((size_t)(bb * 64 + t)) * KVT_BYTES + 32768 +
                      ((size_t)(ksI * 16 + n) << 10) + ((hf * 16 + lo) << 4) + e0 * 2;
        *(us4*)(kv + byte) = pv;
      }
    }
  }
}

// ---------------- Kernel 2a: attn_fa3 (4 waves x 32 rows, LDS-shared KV) ----------------
// 256 blocks x 256 thr. id&7=x: batch=x>>1, chunk-lsb=x&1. v=id>>3 (0..31):
// p=v&15, chunk-msb=v>>4. Tasks: (u=p, cc) then (u=31-p, 3-cc); nt=2u+2,
// chunk cc -> tiles [(nt*cc)>>2, (nt*(cc+1))>>2). ~16.5 tiles/block.
__global__ __launch_bounds__(256, 1) void attn_fa3(
    const char* __restrict__ qbf, const char* __restrict__ kv,
    float* __restrict__ out, unsigned short* __restrict__ o1,
    unsigned short* __restrict__ o2, unsigned short* __restrict__ o3,
    float* __restrict__ ml)
{
  __shared__ char KV_lds[2][KVT_BYTES];        // 128KB double buffer (linear frags)
  __shared__ unsigned short P_lds[4][16][72];

  const int tid = threadIdx.x;
  const int lane = tid & 63;
  const int w = tid >> 6;                      // 0..3
  const int lo = lane & 15, hi = lane >> 4;
  const int id = blockIdx.x;
  const int x = id & 7;
  const int b = x >> 1;
  const int v = id >> 3;
  const int p = v & 15;
  const int cbase = ((v >> 4) << 1) | (x & 1);   // 0..3

  const char* kv_base = kv + (size_t)b * 64 * KVT_BYTES;

  auto stageKV = [&](int t, int buf) {
    const char* src = kv_base + (size_t)t * KVT_BYTES + tid * 16;
    char* dst = &KV_lds[buf][0] + tid * 16;
#pragma unroll
    for (int i = 0; i < 16; ++i) {
      __builtin_amdgcn_global_load_lds(
          (const __attribute__((address_space(1))) void*)(src + i * 4096),
          (__attribute__((address_space(3))) void*)(dst + i * 4096),
          16, 0, 0);
    }
  };

  for (int task = 0; task < 2; ++task) {
    const int u = task ? (31 - p) : p;           // run of 128 q-rows
    const int cc = task ? (3 - cbase) : cbase;
    const int nt = 2 * u + 2;
    const int t0 = (nt * cc) >> 2;
    const int t1 = (nt * (cc + 1)) >> 2;
    const int qrow0 = u * 128 + w * 32;          // strip0 first row (in batch)
    const int rbase = b * SEQ + qrow0;
    float* mlc = ml + (size_t)cc * 16384 * 2;

    if (t0 >= t1) {   // empty chunk (u=0: cc 0 and 2)
      if (lane < 32) {
        mlc[(size_t)(rbase + lane) * 2 + 0] = -3e38f;
        mlc[(size_t)(rbase + lane) * 2 + 1] = 0.f;
      }
      if (cc == 0) {
#pragma unroll
        for (int j = 0; j < 32; j++)
#pragma unroll
          for (int n = 0; n < 4; n++)
            out[(size_t)(rbase + j) * DIM + n * 64 + lane] = 0.f;
      }
      continue;
    }

    // Q fragments pinned: two strips (issued before stages; vmcnt-counted)
    bf16x8 qf0[8], qf1[8];
    {
      const char* qp0 = qbf + ((size_t)(b * 256 + u * 8 + w * 2) << 13) + lane * 16;
      const char* qp1 = qp0 + 8192;
#pragma unroll
      for (int kk = 0; kk < 8; kk++) {
        qf0[kk] = *(const bf16x8*)(qp0 + kk * 1024);
        qf1[kk] = *(const bf16x8*)(qp1 + kk * 1024);
      }
    }

    stageKV(t0, 0);
    if (t0 + 1 < t1) stageKV(t0 + 1, 1);

    float m0r[4], m1r[4], l0r[4], l1r[4];
#pragma unroll
    for (int j = 0; j < 4; j++) { m0r[j] = -3e38f; m1r[j] = -3e38f; l0r[j] = 0.f; l1r[j] = 0.f; }
    f32x4 oa0[16], oa1[16];
#pragma unroll
    for (int n = 0; n < 16; n++) { oa0[n] = (f32x4){0.f,0.f,0.f,0.f}; oa1[n] = (f32x4){0.f,0.f,0.f,0.f}; }

    for (int t = t0; t < t1; ++t) {
      const int cur = (t - t0) & 1;

      // stage(t) complete; stage(t+1)'s 16 loads/thread may stay in flight
      if (t + 1 < t1) {
        asm volatile("s_waitcnt vmcnt(16)" ::: "memory");
      } else {
        asm volatile("s_waitcnt vmcnt(0)" ::: "memory");
      }
      __builtin_amdgcn_sched_barrier(0);
      __builtin_amdgcn_s_barrier();   // buffer cur fully staged for all waves

      const char* kt = &KV_lds[cur][0] + lane * 16;

      // S = Q K^T: K frags from LDS in 4-reg halves, shared by both strips
      f32x4 sf0[4], sf1[4];
      __builtin_amdgcn_s_setprio(1);
#pragma unroll
      for (int nf = 0; nf < 4; nf++) {
        f32x4 a0 = (f32x4){0.f,0.f,0.f,0.f}, a1 = (f32x4){0.f,0.f,0.f,0.f};
#pragma unroll
        for (int h2 = 0; h2 < 2; h2++) {
          bf16x8 kfa[4];
#pragma unroll
          for (int k = 0; k < 4; k++)
            kfa[k] = *(const bf16x8*)(kt + ((nf * 8 + h2 * 4 + k) << 10));
#pragma unroll
          for (int k = 0; k < 4; k++) {
            a0 = __builtin_amdgcn_mfma_f32_16x16x32_bf16(qf0[h2 * 4 + k], kfa[k], a0, 0, 0, 0);
            a1 = __builtin_amdgcn_mfma_f32_16x16x32_bf16(qf1[h2 * 4 + k], kfa[k], a1, 0, 0, 0);
          }
        }
        sf0[nf] = a0; sf1[nf] = a1;
      }
      __builtin_amdgcn_s_setprio(0);

      // causal mask (Q pre-scaled; no scale mul needed)
      if ((t * KVBLK + KVBLK - 1) > qrow0) {
#pragma unroll
        for (int nf = 0; nf < 4; nf++) {
          int kg = t * KVBLK + nf * 16 + lo;
#pragma unroll
          for (int j = 0; j < 4; j++) {
            int qg = qrow0 + hi * 4 + j;
            if (kg > qg) sf0[nf][j] = -__builtin_inff();
            if (kg > qg + 16) sf1[nf][j] = -__builtin_inff();
          }
        }
      }

      // online softmax, defer-max, lazy l (per-lane partials, no in-loop reduce)
      float vn0[4], vn1[4];
#pragma unroll
      for (int j = 0; j < 4; j++) {
        float m = fmaxf(fmaxf(sf0[0][j], sf0[1][j]), fmaxf(sf0[2][j], sf0[3][j]));
        m = fmaxf(m, __shfl_xor(m, 1));
        m = fmaxf(m, __shfl_xor(m, 2));
        m = fmaxf(m, __shfl_xor(m, 4));
        m = fmaxf(m, __shfl_xor(m, 8));
        vn0[j] = m;
      }
#pragma unroll
      for (int j = 0; j < 4; j++) {
        float m = fmaxf(fmaxf(sf1[0][j], sf1[1][j]), fmaxf(sf1[2][j], sf1[3][j]));
        m = fmaxf(m, __shfl_xor(m, 1));
        m = fmaxf(m, __shfl_xor(m, 2));
        m = fmaxf(m, __shfl_xor(m, 4));
        m = fmaxf(m, __shfl_xor(m, 8));
        vn1[j] = m;
      }
      bool grow = false;
#pragma unroll
      for (int j = 0; j < 4; j++)
        grow = grow || (vn0[j] > m0r[j] + 8.f) || (vn1[j] > m1r[j] + 8.f);
      if (__any(grow)) {
#pragma unroll
        for (int j = 0; j < 4; j++) {
          float mn0 = fmaxf(m0r[j], vn0[j]);
          float mn1 = fmaxf(m1r[j], vn1[j]);
          float al0 = __expf(m0r[j] - mn0);
          float al1 = __expf(m1r[j] - mn1);
          m0r[j] = mn0; m1r[j] = mn1;
          l0r[j] *= al0; l1r[j] *= al1;
#pragma unroll
          for (int n = 0; n < 16; n++) { oa0[n][j] *= al0; oa1[n][j] *= al1; }
        }
      }
#pragma unroll
      for (int j = 0; j < 4; j++) {
        float s0 = 0.f, s1 = 0.f;
#pragma unroll
        for (int nf = 0; nf < 4; nf++) {
          sf0[nf][j] = __expf(sf0[nf][j] - m0r[j]); s0 += sf0[nf][j];
          sf1[nf][j] = __expf(sf1[nf][j] - m1r[j]); s1 += sf1[nf][j];
        }
        l0r[j] += s0; l1r[j] += s1;   // per-lane partials; reduced at epilogue
      }

      // P -> per-wave LDS roundtrip, strip-sequential
      bf16x8 pa00, pa01, pa10, pa11;
#pragma unroll
      for (int nf = 0; nf < 4; nf++)
#pragma unroll
        for (int j = 0; j < 4; j++)
          P_lds[w][hi * 4 + j][nf * 16 + lo] = f2bf(sf0[nf][j]);
      asm volatile("s_waitcnt lgkmcnt(0)" ::: "memory");
      __builtin_amdgcn_sched_barrier(0);
      pa00 = *(const bf16x8*)&P_lds[w][lo][hi * 8];
      pa01 = *(const bf16x8*)&P_lds[w][lo][32 + hi * 8];
      asm volatile("s_waitcnt lgkmcnt(0)" ::: "memory");
      __builtin_amdgcn_sched_barrier(0);
#pragma unroll
      for (int nf = 0; nf < 4; nf++)
#pragma unroll
        for (int j = 0; j < 4; j++)
          P_lds[w][hi * 4 + j][nf * 16 + lo] = f2bf(sf1[nf][j]);
      asm volatile("s_waitcnt lgkmcnt(0)" ::: "memory");
      __builtin_amdgcn_sched_barrier(0);
      pa10 = *(const bf16x8*)&P_lds[w][lo][hi * 8];
      pa11 = *(const bf16x8*)&P_lds[w][lo][32 + hi * 8];
      asm volatile("s_waitcnt lgkmcnt(0)" ::: "memory");
      __builtin_amdgcn_sched_barrier(0);

      // O += P V: V frags from LDS, shared by both strips
      const char* vt = &KV_lds[cur][32768] + lane * 16;
      __builtin_amdgcn_s_setprio(1);
#pragma unroll
      for (int g = 0; g < 4; g++) {
        bf16x8 va[4], vb[4];
#pragma unroll
        for (int k = 0; k < 4; k++) {
          int n = g * 4 + k;
          va[k] = *(const bf16x8*)(vt + (n << 10));
          vb[k] = *(const bf16x8*)(vt + ((16 + n) << 10));
        }
#pragma unroll
        for (int k = 0; k < 4; k++) {
          int n = g * 4 + k;
          oa0[n] = __builtin_amdgcn_mfma_f32_16x16x32_bf16(pa00, va[k], oa0[n], 0, 0, 0);
          oa0[n] = __builtin_amdgcn_mfma_f32_16x16x32_bf16(pa01, vb[k], oa0[n], 0, 0, 0);
          oa1[n] = __builtin_amdgcn_mfma_f32_16x16x32_bf16(pa10, va[k], oa1[n], 0, 0, 0);
          oa1[n] = __builtin_amdgcn_mfma_f32_16x16x32_bf16(pa11, vb[k], oa1[n], 0, 0, 0);
        }
      }
      __builtin_amdgcn_s_setprio(0);

      __builtin_amdgcn_sched_barrier(0);
      __builtin_amdgcn_s_barrier();   // all waves done reading buffer cur
      if (t + 2 < t1) stageKV(t + 2, cur);
    }

    // epilogue: reduce lazy-l across 16 lanes; cc==0 -> fp32 out else bf16 partial
    unsigned short* opc = (cc == 1) ? o1 : (cc == 2) ? o2 : o3;
#pragma unroll
    for (int sp = 0; sp < 2; sp++) {
#pragma unroll
      for (int j = 0; j < 4; j++) {
        float lsum = sp ? l1r[j] : l0r[j];
        lsum += __shfl_xor(lsum, 1);
        lsum += __shfl_xor(lsum, 2);
        lsum += __shfl_xor(lsum, 4);
        lsum += __shfl_xor(lsum, 8);
        float mrow = sp ? m1r[j] : m0r[j];
        int r = rbase + sp * 16 + hi * 4 + j;
        float inv = (lsum > 0.f) ? 1.f / lsum : 0.f;
        if (cc == 0) {
          float* orow = out + (size_t)r * DIM;
#pragma unroll
          for (int n = 0; n < 16; n++) {
            f32x4 o = sp ? oa1[n] : oa0[n];
            orow[n * 16 + lo] = o[j] * inv;
          }
        } else {
          unsigned short* orow = opc + (size_t)r * DIM;
#pragma unroll
          for (int n = 0; n < 16; n++) {
            f32x4 o = sp ? oa1[n] : oa0[n];
            orow[n * 16 + lo] = f2bf(o[j] * inv);
          }
        }
        if (lo == 0) {
          mlc[(size_t)r * 2 + 0] = mrow;
          mlc[(size_t)r * 2 + 1] = lsum;
        }
      }
    }
  }
}

// ---------------- Kernel 2b: 4-way merge ----------------
__global__ __launch_bounds__(256) void merge4(
    const float* __restrict__ ml,
    const unsigned short* __restrict__ o1, const unsigned short* __restrict__ o2,
    const unsigned short* __restrict__ o3, float* __restrict__ out)
{
  int r = blockIdx.x * 4 + (threadIdx.x >> 6);
  int c4 = (threadIdx.x & 63) * 4;
  float m0 = ml[(size_t)r*2],           l0 = ml[(size_t)r*2+1];
  float m1 = ml[(size_t)(16384+r)*2],   l1 = ml[(size_t)(16384+r)*2+1];
  float m2 = ml[(size_t)(32768+r)*2],   l2 = ml[(size_t)(32768+r)*2+1];
  float m3 = ml[(size_t)(49152+r)*2],   l3 = ml[(size_t)(49152+r)*2+1];
  float M = fmaxf(fmaxf(m0, m1), fmaxf(m2, m3));
  float w0 = l0 * __expf(m0 - M);
  float w1 = l1 * __expf(m1 - M);
  float w2 = l2 * __expf(m2 - M);
  float w3 = l3 * __expf(m3 - M);
  float inv = 1.f / (w0 + w1 + w2 + w3);
  float4 o0 = *(const float4*)(out + (size_t)r * DIM + c4);
  us4 a  = *(const us4*)(o1 + (size_t)r * DIM + c4);
  us4 bq = *(const us4*)(o2 + (size_t)r * DIM + c4);
  us4 cq = *(const us4*)(o3 + (size_t)r * DIM + c4);
  float4 res;
  res.x = (w0*o0.x + w1*bf2f(a.x) + w2*bf2f(bq.x) + w3*bf2f(cq.x)) * inv;
  res.y = (w0*o0.y + w1*bf2f(a.y) + w2*bf2f(bq.y) + w3*bf2f(cq.y)) * inv;
  res.z = (w0*o0.z + w1*bf2f(a.z) + w2*bf2f(bq.z) + w3*bf2f(cq.z)) * inv;
  res.w = (w0*o0.w + w1*bf2f(a.w) + w2*bf2f(bq.w) + w3*bf2f(cq.w)) * inv;
  *(float4*)(out + (size_t)r * DIM + c4) = res;
}

extern "C" void kernel_launch(void* const* d_in, const int* in_sizes, int n_in,
                              void* d_out, int out_size, void* d_ws, size_t ws_size,
                              hipStream_t stream) {
  const float* x  = (const float*)d_in[0];
  const float* Wq = (const float*)d_in[1];
  const float* Wk = (const float*)d_in[2];
  const float* Wv = (const float*)d_in[3];
  char* ws = (char*)d_ws;
  char* qbf = ws + QB_OFF;
  char* kv  = ws + KV_OFF;
  unsigned short* o1 = (unsigned short*)(ws + O1_OFF);
  unsigned short* o2 = (unsigned short*)(ws + O2_OFF);
  unsigned short* o3 = (unsigned short*)(ws + O3_OFF);
  float* ml = (float*)(ws + ML_OFF);
  float* out = (float*)d_out;

  qkv_gemm<<<dim3(128, 4, 3), 256, 0, stream>>>(x, Wq, Wk, Wv, qbf, kv);
  attn_fa3<<<dim3(256), 256, 0, stream>>>(qbf, kv, out, o1, o2, o3, ml);
  merge4<<<dim3(4096), 256, 0, stream>>>(ml, o1, o2, o3, out);
}

// Round 16
// 97.456 us; speedup vs baseline: 3.4983x; 1.5011x over previous
//
#include <hip/hip_runtime.h>
#include <hip/hip_bf16.h>

// Problem: B=4, S=4096, D=256 single-head causal attention, fp32 in/out.
// ALL tensors in MFMA-fragment order (fragment = contiguous 1KB, lane*16):
//  Qf @0:  strip s16=row>>4: 8KB; frag kk at (s16*8+kk)*1024.
//          Q PRE-SCALED by 0.0625*log2(e) -> scores are in LOG2 domain:
//          softmax uses bare exp2 (v_exp_f32 native), no per-tile scale mul.
//  KV @8MB: per (batch, kv-tile t<64) 64KB: K frags [0..32K) (nf*8+kk)*1024;
//           V frags [32K..64K) (ks*16+n)*1024
//  O1/O2/O3 bf16 partials @24/32/40MB; ML fp32 [4][16384][2] @48MB (m in log2).
// attn_fa: R12-proven geometry: 256 blocks x 512 thr (8 waves x 16 rows,
// 1 block/CU, 2 waves/SIMD — R15 A/B: 2/SIMD TLP beats 2-strip at 1/SIMD).
// Runs of 128 rows (u=0..31, nt=2u+2), complement pairs (p,cc)+(31-p,3-cc).
// Micro-opts this round: lazy-l, log2-softmax, setprio around MFMA.
// qkv_gemm: fused z (Q,K,V in one block) -> x read once, 512 blocks.

#define SEQ 4096
#define DIM 256
#define NBATCH 4
#define KVBLK 64
#define KVT_BYTES 65536

#define QB_OFF   0
#define KV_OFF   (8u*1024*1024)
#define O1_OFF   (24u*1024*1024)
#define O2_OFF   (32u*1024*1024)
#define O3_OFF   (40u*1024*1024)
#define ML_OFF   (48u*1024*1024)

// 0.0625 * log2(e)
#define QSCALE 0.09016844f
// 8 nats in bits
#define DEFER_THR 11.5415603f

typedef __attribute__((ext_vector_type(8))) short bf16x8;
typedef __attribute__((ext_vector_type(4))) float f32x4;
typedef __attribute__((ext_vector_type(4))) unsigned short us4;

static __device__ inline unsigned short f2bf(float f) {
  unsigned int u = __float_as_uint(f);
  u += 0x7FFFu + ((u >> 16) & 1u);
  return (unsigned short)(u >> 16);
}
static __device__ inline float bf2f(unsigned short u) {
  return __uint_as_float(((unsigned int)u) << 16);
}

// ---------------- Kernel 1: fused QKV projection (z fused; x read once) ----------------
// grid (128, 4), block 256 (4 waves, 2 blocks/CU).
__global__ __launch_bounds__(256) void qkv_gemm(
    const float* __restrict__ x, const float* __restrict__ Wq,
    const float* __restrict__ Wk, const float* __restrict__ Wv,
    char* __restrict__ qbf, char* __restrict__ kv)
{
  __shared__ unsigned short A_lds[128][40];
  __shared__ unsigned short B_lds[3][64][40];

  const int tid = threadIdx.x;
  const int lane = tid & 63;
  const int w = tid >> 6;
  const int lo = lane & 15, hi = lane >> 4;
  const int mb = blockIdx.x * 128;
  const int nb = blockIdx.y * 64;
  const float* Ws[3] = { Wq, Wk, Wv };

  f32x4 acc[3][2][4];
#pragma unroll
  for (int z = 0; z < 3; z++)
#pragma unroll
    for (int mi = 0; mi < 2; mi++)
#pragma unroll
      for (int ni = 0; ni < 4; ni++) acc[z][mi][ni] = (f32x4){0.f, 0.f, 0.f, 0.f};

  for (int ks = 0; ks < 8; ++ks) {
    const int k0 = ks * 32;
    __syncthreads();
#pragma unroll
    for (int i = 0; i < 4; ++i) {
      int f = tid + i * 256;
      int row = f >> 3, c4 = (f & 7) * 4;
      float4 v = *(const float4*)(x + (size_t)(mb + row) * DIM + k0 + c4);
      us4 bv = { f2bf(v.x), f2bf(v.y), f2bf(v.z), f2bf(v.w) };
      *(us4*)&A_lds[row][c4] = bv;
    }
#pragma unroll
    for (int z = 0; z < 3; z++)
#pragma unroll
      for (int i = 0; i < 2; ++i) {
        int f = tid + i * 256;
        int row = f >> 3, c4 = (f & 7) * 4;
        float4 v = *(const float4*)(Ws[z] + (size_t)(nb + row) * DIM + k0 + c4);
        us4 bv = { f2bf(v.x), f2bf(v.y), f2bf(v.z), f2bf(v.w) };
        *(us4*)&B_lds[z][row][c4] = bv;
      }
    __syncthreads();
    bf16x8 a[2];
#pragma unroll
    for (int mi = 0; mi < 2; mi++) a[mi] = *(const bf16x8*)&A_lds[w * 32 + mi * 16 + lo][hi * 8];
#pragma unroll
    for (int z = 0; z < 3; z++) {
      bf16x8 bfr[4];
#pragma unroll
      for (int ni = 0; ni < 4; ni++) bfr[ni] = *(const bf16x8*)&B_lds[z][ni * 16 + lo][hi * 8];
#pragma unroll
      for (int mi = 0; mi < 2; mi++)
#pragma unroll
        for (int ni = 0; ni < 4; ni++)
          acc[z][mi][ni] = __builtin_amdgcn_mfma_f32_16x16x32_bf16(a[mi], bfr[ni], acc[z][mi][ni], 0, 0, 0);
    }
  }

  // Q epilogue (fragment order, pre-scaled into log2 domain)
#pragma unroll
  for (int mi = 0; mi < 2; mi++) {
    int r0 = mb + w * 32 + mi * 16 + hi * 4;
#pragma unroll
    for (int ni = 0; ni < 4; ni++) {
      int d = nb + ni * 16 + lo;
      int kkq = d >> 5, hiq = (d >> 3) & 3, eq = d & 7;
#pragma unroll
      for (int j = 0; j < 4; j++) {
        int srow = r0 + j;
        int s16 = srow >> 4, loq = srow & 15;
        size_t byte = ((size_t)(s16 * 8 + kkq) << 10) + ((hiq * 16 + loq) << 4) + eq * 2;
        *(unsigned short*)(qbf + byte) = f2bf(acc[0][mi][ni][j] * QSCALE);
      }
    }
  }
  // K epilogue (fragment order)
#pragma unroll
  for (int mi = 0; mi < 2; mi++) {
    int r0 = mb + w * 32 + mi * 16 + hi * 4;
#pragma unroll
    for (int ni = 0; ni < 4; ni++) {
      int d = nb + ni * 16 + lo;
      int kkk = d >> 5, hik = (d >> 3) & 3, ek = d & 7;
#pragma unroll
      for (int j = 0; j < 4; j++) {
        int srow = r0 + j;
        int bb = srow >> 12, sl = srow & 4095;
        int t = sl >> 6, r = sl & 63;
        int nf = r >> 4, lok = r & 15;
        size_t byte = ((size_t)(bb * 64 + t)) * KVT_BYTES +
                      ((size_t)(nf * 8 + kkk) << 10) + ((hik * 16 + lok) << 4) + ek * 2;
        *(unsigned short*)(kv + byte) = f2bf(acc[1][mi][ni][j]);
      }
    }
  }
  // V epilogue (fragment order, 8B stores)
#pragma unroll
  for (int mi = 0; mi < 2; mi++) {
    int s0 = mb + w * 32 + mi * 16 + hi * 4;
    int bb = s0 >> 12;
    int t = (s0 >> 6) & 63;
    int s_t = s0 & 63;
    int ksI = s_t >> 5;
    int hf = (s_t >> 3) & 3;
    int e0 = s_t & 7;
#pragma unroll
    for (int ni = 0; ni < 4; ni++) {
      int d = nb + ni * 16 + lo;
      int n = d >> 4;
      us4 pv = { f2bf(acc[2][mi][ni][0]), f2bf(acc[2][mi][ni][1]),
                 f2bf(acc[2][mi][ni][2]), f2bf(acc[2][mi][ni][3]) };
      size_t byte = ((size_t)(bb * 64 + t)) * KVT_BYTES + 32768 +
                    ((size_t)(ksI * 16 + n) << 10) + ((hf * 16 + lo) << 4) + e0 * 2;
      *(us4*)(kv + byte) = pv;
    }
  }
}

// ---------------- Kernel 2a: attn_fa (8 waves x 16 rows, LDS-shared KV) ----------------
// 256 blocks x 512 thr. id&7=x: batch=x>>1, chunk-lsb=x&1. v=id>>3 (0..31):
// p=v&15, chunk-msb=v>>4. Tasks: (u=p, cc) then (u=31-p, 3-cc); nt=2u+2,
// chunk cc -> tiles [(nt*cc)>>2, (nt*(cc+1))>>2). ~16.5 tiles/block.
__global__ __launch_bounds__(512, 1) void attn_fa(
    const char* __restrict__ qbf, const char* __restrict__ kv,
    float* __restrict__ out, unsigned short* __restrict__ o1,
    unsigned short* __restrict__ o2, unsigned short* __restrict__ o3,
    float* __restrict__ ml)
{
  __shared__ char KV_lds[2][KVT_BYTES];        // 128KB double buffer (linear frags)
  __shared__ unsigned short P_lds[8][16][72];

  const int tid = threadIdx.x;
  const int lane = tid & 63;
  const int w = tid >> 6;
  const int lo = lane & 15, hi = lane >> 4;
  const int id = blockIdx.x;
  const int x = id & 7;
  const int b = x >> 1;
  const int v = id >> 3;
  const int p = v & 15;
  const int cbase = ((v >> 4) << 1) | (x & 1);   // 0..3

  const char* kv_base = kv + (size_t)b * 64 * KVT_BYTES;

  auto stageKV = [&](int t, int buf) {
    const char* src = kv_base + (size_t)t * KVT_BYTES + tid * 16;
    char* dst = &KV_lds[buf][0] + tid * 16;
#pragma unroll
    for (int i = 0; i < 8; ++i) {
      __builtin_amdgcn_global_load_lds(
          (const __attribute__((address_space(1))) void*)(src + i * 8192),
          (__attribute__((address_space(3))) void*)(dst + i * 8192),
          16, 0, 0);
    }
  };

  for (int task = 0; task < 2; ++task) {
    const int u = task ? (15 - p) + 16 : p;      // run: p then 31-p
    const int cc = task ? (3 - cbase) : cbase;
    const int nt = 2 * u + 2;
    const int t0 = (nt * cc) >> 2;
    const int t1 = (nt * (cc + 1)) >> 2;
    const int qrow0 = u * 128 + w * 16;          // wave's first q row (in batch)
    const int rbase = b * SEQ + qrow0;
    float* mlc = ml + (size_t)cc * 16384 * 2;

    if (t0 >= t1) {   // empty chunk (u=0: cc 0 and 2)
      if (lane < 16) {
        mlc[(size_t)(rbase + lane) * 2 + 0] = -3e38f;
        mlc[(size_t)(rbase + lane) * 2 + 1] = 0.f;
      }
      if (cc == 0) {
#pragma unroll
        for (int j = 0; j < 16; j++)
#pragma unroll
          for (int n = 0; n < 4; n++)
            out[(size_t)(rbase + j) * DIM + n * 64 + lane] = 0.f;
      }
      continue;
    }

    // Q fragments pinned (issued BEFORE stages; vmcnt-counted together)
    bf16x8 qf[8];
    {
      const char* qp = qbf + ((size_t)(b * 256 + u * 8 + w) << 13) + lane * 16;
#pragma unroll
      for (int kk = 0; kk < 8; kk++)
        qf[kk] = *(const bf16x8*)(qp + kk * 1024);
    }

    stageKV(t0, 0);
    if (t0 + 1 < t1) stageKV(t0 + 1, 1);

    float m_run[4], l_run[4];
#pragma unroll
    for (int j = 0; j < 4; j++) { m_run[j] = -3e38f; l_run[j] = 0.f; }
    f32x4 o_acc[16];
#pragma unroll
    for (int n = 0; n < 16; n++) o_acc[n] = (f32x4){0.f, 0.f, 0.f, 0.f};

    for (int t = t0; t < t1; ++t) {
      const int cur = (t - t0) & 1;

      // stage(t) complete; stage(t+1)'s 8 loads/thread may stay in flight
      if (t + 1 < t1) {
        asm volatile("s_waitcnt vmcnt(8)" ::: "memory");
      } else {
        asm volatile("s_waitcnt vmcnt(0)" ::: "memory");
      }
      __builtin_amdgcn_sched_barrier(0);
      __builtin_amdgcn_s_barrier();   // buffer cur fully staged for all waves

      const char* kt = &KV_lds[cur][0] + lane * 16;

      // S' = Q K^T (log2 domain; Q pre-scaled)
      f32x4 sf[4];
      __builtin_amdgcn_s_setprio(1);
#pragma unroll
      for (int nf = 0; nf < 4; nf++) {
        bf16x8 kf[8];
#pragma unroll
        for (int kk = 0; kk < 8; kk++)
          kf[kk] = *(const bf16x8*)(kt + ((nf * 8 + kk) << 10));
        f32x4 a = (f32x4){0.f, 0.f, 0.f, 0.f};
#pragma unroll
        for (int kk = 0; kk < 8; kk++)
          a = __builtin_amdgcn_mfma_f32_16x16x32_bf16(qf[kk], kf[kk], a, 0, 0, 0);
        sf[nf] = a;
      }
      __builtin_amdgcn_s_setprio(0);

      // causal mask (no scale mul — already folded into Q)
      if ((t * KVBLK + KVBLK - 1) > qrow0) {
#pragma unroll
        for (int nf = 0; nf < 4; nf++) {
          int kg = t * KVBLK + nf * 16 + lo;
#pragma unroll
          for (int j = 0; j < 4; j++) {
            int qg = qrow0 + hi * 4 + j;
            if (kg > qg) sf[nf][j] = -__builtin_inff();
          }
        }
      }

      // online softmax in log2 domain: defer-max + lazy-l
      float vnew[4];
#pragma unroll
      for (int j = 0; j < 4; j++) {
        float m = fmaxf(fmaxf(sf[0][j], sf[1][j]), fmaxf(sf[2][j], sf[3][j]));
        m = fmaxf(m, __shfl_xor(m, 1));
        m = fmaxf(m, __shfl_xor(m, 2));
        m = fmaxf(m, __shfl_xor(m, 4));
        m = fmaxf(m, __shfl_xor(m, 8));
        vnew[j] = m;
      }
      bool grow = false;
#pragma unroll
      for (int j = 0; j < 4; j++) grow = grow || (vnew[j] > m_run[j] + DEFER_THR);
      if (__any(grow)) {
#pragma unroll
        for (int j = 0; j < 4; j++) {
          float mn = fmaxf(m_run[j], vnew[j]);
          float alpha = exp2f(m_run[j] - mn);
          m_run[j] = mn;
          l_run[j] *= alpha;
#pragma unroll
          for (int n = 0; n < 16; n++) o_acc[n][j] *= alpha;
        }
      }
#pragma unroll
      for (int j = 0; j < 4; j++) {
        float sum = 0.f;
#pragma unroll
        for (int nf = 0; nf < 4; nf++) {
          sf[nf][j] = exp2f(sf[nf][j] - m_run[j]);
          sum += sf[nf][j];
        }
        l_run[j] += sum;   // per-lane partial; reduced once at epilogue
      }

      // P -> per-wave LDS roundtrip
#pragma unroll
      for (int nf = 0; nf < 4; nf++)
#pragma unroll
        for (int j = 0; j < 4; j++)
          P_lds[w][hi * 4 + j][nf * 16 + lo] = f2bf(sf[nf][j]);
      asm volatile("s_waitcnt lgkmcnt(0)" ::: "memory");
      __builtin_amdgcn_sched_barrier(0);
      bf16x8 pa0 = *(const bf16x8*)&P_lds[w][lo][hi * 8];
      bf16x8 pa1 = *(const bf16x8*)&P_lds[w][lo][32 + hi * 8];
      asm volatile("s_waitcnt lgkmcnt(0)" ::: "memory");
      __builtin_amdgcn_sched_barrier(0);

      // O += P V (V frags from LDS)
      const char* vt = &KV_lds[cur][32768] + lane * 16;
      __builtin_amdgcn_s_setprio(1);
#pragma unroll
      for (int g = 0; g < 4; g++) {
        bf16x8 va[4], vb[4];
#pragma unroll
        for (int k = 0; k < 4; k++) {
          int n = g * 4 + k;
          va[k] = *(const bf16x8*)(vt + (n << 10));
          vb[k] = *(const bf16x8*)(vt + ((16 + n) << 10));
        }
#pragma unroll
        for (int k = 0; k < 4; k++) {
          o_acc[g * 4 + k] = __builtin_amdgcn_mfma_f32_16x16x32_bf16(pa0, va[k], o_acc[g * 4 + k], 0, 0, 0);
          o_acc[g * 4 + k] = __builtin_amdgcn_mfma_f32_16x16x32_bf16(pa1, vb[k], o_acc[g * 4 + k], 0, 0, 0);
        }
      }
      __builtin_amdgcn_s_setprio(0);

      __builtin_amdgcn_sched_barrier(0);
      __builtin_amdgcn_s_barrier();   // all waves done reading buffer cur
      if (t + 2 < t1) stageKV(t + 2, cur);
    }

    // epilogue: reduce lazy-l across 16 lanes; cc==0 -> fp32 out else bf16 partial
    unsigned short* opc = (cc == 1) ? o1 : (cc == 2) ? o2 : o3;
#pragma unroll
    for (int j = 0; j < 4; j++) {
      float lsum = l_run[j];
      lsum += __shfl_xor(lsum, 1);
      lsum += __shfl_xor(lsum, 2);
      lsum += __shfl_xor(lsum, 4);
      lsum += __shfl_xor(lsum, 8);
      int r = rbase + hi * 4 + j;
      float inv = (lsum > 0.f) ? 1.f / lsum : 0.f;
      if (cc == 0) {
        float* orow = out + (size_t)r * DIM;
#pragma unroll
        for (int n = 0; n < 16; n++)
          orow[n * 16 + lo] = o_acc[n][j] * inv;
      } else {
        unsigned short* orow = opc + (size_t)r * DIM;
#pragma unroll
        for (int n = 0; n < 16; n++)
          orow[n * 16 + lo] = f2bf(o_acc[n][j] * inv);
      }
      if (lo == 0) {
        mlc[(size_t)r * 2 + 0] = m_run[j];
        mlc[(size_t)r * 2 + 1] = lsum;
      }
    }
  }
}

// ---------------- Kernel 2b: 4-way merge (m in log2 domain -> exp2) ----------------
__global__ __launch_bounds__(256) void merge4(
    const float* __restrict__ ml,
    const unsigned short* __restrict__ o1, const unsigned short* __restrict__ o2,
    const unsigned short* __restrict__ o3, float* __restrict__ out)
{
  int r = blockIdx.x * 4 + (threadIdx.x >> 6);
  int c4 = (threadIdx.x & 63) * 4;
  float m0 = ml[(size_t)r*2],           l0 = ml[(size_t)r*2+1];
  float m1 = ml[(size_t)(16384+r)*2],   l1 = ml[(size_t)(16384+r)*2+1];
  float m2 = ml[(size_t)(32768+r)*2],   l2 = ml[(size_t)(32768+r)*2+1];
  float m3 = ml[(size_t)(49152+r)*2],   l3 = ml[(size_t)(49152+r)*2+1];
  float M = fmaxf(fmaxf(m0, m1), fmaxf(m2, m3));
  float w0 = l0 * exp2f(m0 - M);
  float w1 = l1 * exp2f(m1 - M);
  float w2 = l2 * exp2f(m2 - M);
  float w3 = l3 * exp2f(m3 - M);
  float inv = 1.f / (w0 + w1 + w2 + w3);
  float4 o0 = *(const float4*)(out + (size_t)r * DIM + c4);
  us4 a  = *(const us4*)(o1 + (size_t)r * DIM + c4);
  us4 bq = *(const us4*)(o2 + (size_t)r * DIM + c4);
  us4 cq = *(const us4*)(o3 + (size_t)r * DIM + c4);
  float4 res;
  res.x = (w0*o0.x + w1*bf2f(a.x) + w2*bf2f(bq.x) + w3*bf2f(cq.x)) * inv;
  res.y = (w0*o0.y + w1*bf2f(a.y) + w2*bf2f(bq.y) + w3*bf2f(cq.y)) * inv;
  res.z = (w0*o0.z + w1*bf2f(a.z) + w2*bf2f(bq.z) + w3*bf2f(cq.z)) * inv;
  res.w = (w0*o0.w + w1*bf2f(a.w) + w2*bf2f(bq.w) + w3*bf2f(cq.w)) * inv;
  *(float4*)(out + (size_t)r * DIM + c4) = res;
}

extern "C" void kernel_launch(void* const* d_in, const int* in_sizes, int n_in,
                              void* d_out, int out_size, void* d_ws, size_t ws_size,
                              hipStream_t stream) {
  const float* x  = (const float*)d_in[0];
  const float* Wq = (const float*)d_in[1];
  const float* Wk = (const float*)d_in[2];
  const float* Wv = (const float*)d_in[3];
  char* ws = (char*)d_ws;
  char* qbf = ws + QB_OFF;
  char* kv  = ws + KV_OFF;
  unsigned short* o1 = (unsigned short*)(ws + O1_OFF);
  unsigned short* o2 = (unsigned short*)(ws + O2_OFF);
  unsigned short* o3 = (unsigned short*)(ws + O3_OFF);
  float* ml = (float*)(ws + ML_OFF);
  float* out = (float*)d_out;

  qkv_gemm<<<dim3(128, 4), 256, 0, stream>>>(x, Wq, Wk, Wv, qbf, kv);
  attn_fa<<<dim3(256), 512, 0, stream>>>(qbf, kv, out, o1, o2, o3, ml);
  merge4<<<dim3(4096), 256, 0, stream>>>(ml, o1, o2, o3, out);
}